// Round 7
// baseline (337.250 us; speedup 1.0000x reference)
//
#include <hip/hip_runtime.h>
#include <stdint.h>

// Trilinear grid_sample of 256^3 fp32 volume, x100. Round 7: z-slab L2
// residency with PHYSICAL XCD pinning.
//   scatter: route points into 16 z-slab buckets (16 planes = 4 MB fp32 =
//            one XCD's L2). recs in contiguous runs; inv[i]=slot coalesced.
//   gather (x2, phase 0/1): each block reads hwreg(HW_REG_XCC_ID) and serves
//            slab phase*8+xcc -> taps hit its OWN L2. Kernel boundary is the
//            device-wide phase barrier. Work claimed via per-slab cursors +
//            stealing, so correctness NEVER depends on the XCD mapping.
//   combine: out[i] = result[inv[i]] -- random 4B READS over 2.6 MB only.
// Lessons: no NT scatter-stores, no global atomics in hot data path (R4/R5);
// dispatch-order phase separation is fiction (R6) -> physical XCC_ID + two
// launches. Streams use NT so they don't evict the resident slab.

#define NSLAB 16
#define OVCAP 16384

typedef float v4f __attribute__((ext_vector_type(4)));

__device__ __forceinline__ int xcc_id() {
  unsigned v;
  asm volatile("s_getreg_b32 %0, hwreg(HW_REG_XCC_ID)" : "=s"(v));
  return (int)(v & 7);
}

// ---------- scatter: histogram + reservation + record write ---------------
__global__ __launch_bounds__(1024) void scatter_kernel(
    const float* __restrict__ x,
    uint32_t* __restrict__ cur,      // [NSLAB] fill counts (pre-zeroed)
    uint32_t* __restrict__ ovn,      // overflow count (pre-zeroed)
    uint32_t* __restrict__ ovbkt,    // [OVCAP]
    v4f* __restrict__ ovrec,         // [OVCAP] (.w = dest index)
    v4f* __restrict__ recs,          // [NSLAB * cap]
    uint32_t* __restrict__ inv,      // [n] point -> global slot
    int cap, int n)
{
  __shared__ uint32_t lh[NSLAB];
  __shared__ uint32_t gb[NSLAB];
  int t = threadIdx.x;
  if (t < NSLAB) lh[t] = 0;
  __syncthreads();

  int i = blockIdx.x * 1024 + t;
  bool act = (i < n);
  float ix = 0.f, iy = 0.f, iz = 0.f;
  int b = 0;
  uint32_t lr = 0;
  if (act) {
    float gx = x[3 * i + 0] * 2.0f;
    float gy = x[3 * i + 1] * 2.0f;
    float gz = x[3 * i + 2] * 2.0f;
    ix = ((gx + 1.0f) * 256.0f - 1.0f) * 0.5f;
    iy = ((gy + 1.0f) * 256.0f - 1.0f) * 0.5f;
    iz = ((gz + 1.0f) * 256.0f - 1.0f) * 0.5f;
    int z0 = (int)floorf(iz);                 // [-1, 255]
    b = min(max(z0, 0), 255) >> 4;            // slab of zA
    lr = atomicAdd(&lh[b], 1u);
  }
  __syncthreads();

  if (t < NSLAB) {
    uint32_t c = lh[t];
    gb[t] = c ? atomicAdd(&cur[t], c) : 0u;   // one global atomic per (block,slab)
  }
  __syncthreads();

  if (act) {
    uint32_t p = gb[b] + lr;
    if (p < (uint32_t)cap) {
      uint32_t slot = (uint32_t)b * cap + p;
      v4f r = { ix, iy, iz, 0.0f };
      recs[slot] = r;                         // contiguous runs -> L2 absorbs
      inv[i] = slot;                          // coalesced
    } else {
      uint32_t o = atomicAdd(ovn, 1u);
      if (o < OVCAP) {
        ovbkt[o] = (uint32_t)b;
        v4f r = { ix, iy, iz, __uint_as_float((uint32_t)i) };
        ovrec[o] = r;
      }
      inv[i] = 0xFFFFFFFFu;                   // gather writes out[] directly
    }
  }
}

// ---------- trilerp from global (L2-resident slab) ------------------------
__device__ __forceinline__ float trilerp_g(
    const float* __restrict__ vol, float ix, float iy, float iz)
{
  float x0f = floorf(ix), y0f = floorf(iy), z0f = floorf(iz);
  float tx = ix - x0f, ty = iy - y0f, tz = iz - z0f;
  int x0 = (int)x0f, y0 = (int)y0f, z0 = (int)z0f;
  float wx0 = (x0 >= 0 && x0 < 256) ? (1.0f - tx) : 0.0f;
  float wx1 = (x0 + 1 >= 0 && x0 + 1 < 256) ? tx : 0.0f;
  float wy0 = (y0 >= 0 && y0 < 256) ? (1.0f - ty) : 0.0f;
  float wy1 = (y0 + 1 >= 0 && y0 + 1 < 256) ? ty : 0.0f;
  float wz0 = (z0 >= 0 && z0 < 256) ? (1.0f - tz) : 0.0f;
  float wz1 = (z0 + 1 >= 0 && z0 + 1 < 256) ? tz : 0.0f;
  int xc0 = min(max(x0, 0), 255), xc1 = min(max(x0 + 1, 0), 255);
  int yc0 = min(max(y0, 0), 255), yc1 = min(max(y0 + 1, 0), 255);
  int zc0 = min(max(z0, 0), 255), zc1 = min(max(z0 + 1, 0), 255);
  int r00 = (zc0 * 256 + yc0) * 256;
  int r01 = (zc0 * 256 + yc1) * 256;
  int r10 = (zc1 * 256 + yc0) * 256;
  int r11 = (zc1 * 256 + yc1) * 256;
  float v000 = vol[r00 + xc0], v001 = vol[r00 + xc1];
  float v010 = vol[r01 + xc0], v011 = vol[r01 + xc1];
  float v100 = vol[r10 + xc0], v101 = vol[r10 + xc1];
  float v110 = vol[r11 + xc0], v111 = vol[r11 + xc1];
  float c00 = v000 * wx0 + v001 * wx1;
  float c01 = v010 * wx0 + v011 * wx1;
  float c10 = v100 * wx0 + v101 * wx1;
  float c11 = v110 * wx0 + v111 * wx1;
  float c0 = c00 * wy0 + c01 * wy1;
  float c1 = c10 * wy0 + c11 * wy1;
  return 100.0f * (c0 * wz0 + c1 * wz1);
}

// ---------- gather (one phase = 8 slabs, slab s -> XCD s&7) ---------------
__global__ __launch_bounds__(256) void gather_kernel(
    const float* __restrict__ vol,
    const v4f* __restrict__ recs,
    const uint32_t* __restrict__ cur,
    uint32_t* __restrict__ rank,     // [NSLAB] registration (pre-zeroed)
    uint32_t* __restrict__ cursor,   // [NSLAB] work cursors (pre-zeroed)
    const uint32_t* __restrict__ ovn,
    const uint32_t* __restrict__ ovbkt,
    const v4f* __restrict__ ovrec,
    float* __restrict__ result,
    float* __restrict__ out,
    float* __restrict__ sink,
    int cap, int phase)
{
  __shared__ uint32_t sh_rank, sh_chunk;
  int xcc = xcc_id();
  int s_own = phase * 8 + xcc;

  if (threadIdx.x == 0) sh_rank = atomicAdd(&rank[s_own], 1u);
  __syncthreads();
  uint32_t r = sh_rank & 127;          // ~128 blocks/XCD expected

  // warm this block's 32 KB chunk of the 4 MB slab (coalesced, full lines)
  const v4f* slab4 = (const v4f*)(vol + (size_t)s_own * 16 * 65536);
  float acc = 0.0f;
  for (int e = 0; e < 8; ++e) {
    v4f v = slab4[r * 2048 + e * 256 + threadIdx.x];
    acc += v.x + v.y + v.z + v.w;
  }
  if (__float_as_uint(acc) == 0xDEADBEEFu) *sink = acc;  // keep loads alive

  // own slab first, then steal across the phase (correct for ANY xcc value)
  for (int t = 0; t < 8; ++t) {
    int s = phase * 8 + ((xcc + t) & 7);
    uint32_t cnt = min(cur[s], (uint32_t)cap);
    const v4f* rb = recs + (size_t)s * cap;
    float* resb = result + (size_t)s * cap;
    while (true) {
      if (threadIdx.x == 0) sh_chunk = atomicAdd(&cursor[s], 256u);
      __syncthreads();
      uint32_t c0 = sh_chunk;
      __syncthreads();
      if (c0 >= cnt) break;
      uint32_t j = c0 + threadIdx.x;
      if (j < cnt) {
        v4f rec = __builtin_nontemporal_load(&rb[j]);    // stream, don't cache
        float v = trilerp_g(vol, rec.x, rec.y, rec.z);   // taps: L2-resident
        __builtin_nontemporal_store(v, &resb[j]);        // coalesced full lines
      }
    }
  }

  // exact overflow handling (statistically never; idempotent across blocks)
  uint32_t nov = min(*ovn, (uint32_t)OVCAP);
  for (uint32_t j = threadIdx.x; j < nov; j += 256) {
    uint32_t b = ovbkt[j];
    if ((int)(b >> 3) == phase) {
      v4f rr = ovrec[j];
      out[__float_as_uint(rr.w)] = trilerp_g(vol, rr.x, rr.y, rr.z);
    }
  }
}

// ---------- combine: permute result back to point order -------------------
__global__ __launch_bounds__(256) void combine_kernel(
    const float* __restrict__ result,
    const uint32_t* __restrict__ inv,
    float* __restrict__ out, int n)
{
  int i = blockIdx.x * 256 + threadIdx.x;
  if (i < n) {
    uint32_t s = inv[i];               // coalesced
    if (s != 0xFFFFFFFFu)
      out[i] = result[s];              // random 4B READ over 2.6 MB
  }
}

// ---------- fallback: direct gather (R1 kernel) ---------------------------
__global__ __launch_bounds__(256) void direct_kernel(
    const float* __restrict__ x, const float* __restrict__ vol,
    float* __restrict__ out, int n)
{
  int i = blockIdx.x * blockDim.x + threadIdx.x;
  if (i >= n) return;
  float gx = x[3 * i + 0] * 2.0f;
  float gy = x[3 * i + 1] * 2.0f;
  float gz = x[3 * i + 2] * 2.0f;
  float ix = ((gx + 1.0f) * 256.0f - 1.0f) * 0.5f;
  float iy = ((gy + 1.0f) * 256.0f - 1.0f) * 0.5f;
  float iz = ((gz + 1.0f) * 256.0f - 1.0f) * 0.5f;
  out[i] = trilerp_g(vol, ix, iy, iz);
}

extern "C" void kernel_launch(void* const* d_in, const int* in_sizes, int n_in,
                              void* d_out, int out_size, void* d_ws, size_t ws_size,
                              hipStream_t stream) {
  const float* x   = (const float*)d_in[0];   // [8, 65536, 3] fp32
  const float* vol = (const float*)d_in[1];   // [256,256,256] fp32
  float* out = (float*)d_out;                 // [8, 65536] fp32
  int n = out_size;                           // 524288

  int m = (n + NSLAB - 1) / NSLAB;            // mean per slab (32768)
  int cap = m + m / 4 + 64;                   // +25% (sigma ~180 -> never overflows)

  // workspace layout
  const size_t ovbkt_off = 8192;                       // OVCAP u32 = 64 KB
  const size_t ovrec_off = ovbkt_off + OVCAP * 4;      // OVCAP v4f = 256 KB
  size_t recs_off  = ovrec_off + (size_t)OVCAP * 16;
  size_t recs_b    = (size_t)NSLAB * cap * 16;
  size_t res_off   = recs_off + recs_b;
  size_t res_b     = (size_t)NSLAB * cap * 4;
  size_t inv_off   = res_off + res_b;
  size_t need      = inv_off + (size_t)n * 4;          // ~15.7 MB

  if (ws_size >= need && n == 524288) {
    char* ws = (char*)d_ws;
    uint32_t* cur    = (uint32_t*)(ws + 0);       // 16 u32
    uint32_t* rank   = (uint32_t*)(ws + 256);     // 16 u32
    uint32_t* cursor = (uint32_t*)(ws + 512);     // 16 u32
    uint32_t* ovn    = (uint32_t*)(ws + 1024);
    float*    sink   = (float*)(ws + 6144);
    uint32_t* ovbkt  = (uint32_t*)(ws + ovbkt_off);
    v4f*      ovrec  = (v4f*)(ws + ovrec_off);
    v4f*      recs   = (v4f*)(ws + recs_off);
    float*    result = (float*)(ws + res_off);
    uint32_t* inv    = (uint32_t*)(ws + inv_off);

    (void)hipMemsetAsync(ws, 0, 8192, stream);    // cur+rank+cursor+ovn
    scatter_kernel<<<n / 1024, 1024, 0, stream>>>(
        x, cur, ovn, ovbkt, ovrec, recs, inv, cap, n);
    gather_kernel<<<1024, 256, 0, stream>>>(
        vol, recs, cur, rank, cursor, ovn, ovbkt, ovrec, result, out, sink, cap, 0);
    gather_kernel<<<1024, 256, 0, stream>>>(
        vol, recs, cur, rank, cursor, ovn, ovbkt, ovrec, result, out, sink, cap, 1);
    combine_kernel<<<(n + 255) / 256, 256, 0, stream>>>(result, inv, out, n);
  } else {
    direct_kernel<<<(n + 255) / 256, 256, 0, stream>>>(x, vol, out, n);
  }
}